// Round 12
// baseline (657.135 us; speedup 1.0000x reference)
//
#include <hip/hip_runtime.h>
#include <hip/hip_bf16.h>

// GraphConv: out = verts@W0^T + b0 + scatter_sum_undirected(verts@W1^T + b1)
// V=100000, E=1000000, D=64. fp32 in/out; edges int64 (or int32) detected.
//
// R11 -> R12: CSR build deleted. R11 falsified the "competing stream" theory
// (phase-B fill: same 87us/80MB WRITE with only 2MB bin reads) -> the floor
// is the 2M cnt/col line-RMWs themselves. New structure:
//   bin (R11, 25us): edges -> 8 per-XCD bins of packed (t_local<<17|n).
//   scatter_fused: XCD x's sub-grid consumes bin x; per entry the wave
//     gathers vbf[n] (128B bf16 row, nontemporal -> no L2 pollution) and
//     wave-wide fp32-atomicAdd's into sums[t] (3.2MB/XCD partition, L2-
//     resident) + lane0 degree count. Replaces fill+gather+spill+col.
//   matvec (R10, verified MFMA) unchanged.

#define NV 100000
#define NE 1000000
#define DIM 64
#define NXCD 8
#define VPERX ((NV + NXCD - 1) / NXCD)   // 12500 vertices per XCD partition
#define NTILE (NV / 16)                  // 6250 MFMA row-tiles
#define CAPB 525000                      // bin capacity (expected 250k/XCD)
#define ABLK 2048
#define CHUNK ((NE + ABLK - 1) / ABLK)   // 489 edges per phase-A block

typedef __attribute__((ext_vector_type(8))) short short8;   // 8 bf16
typedef __attribute__((ext_vector_type(4))) float f32x4;

// ---------------------------------------------------------------------------
// Edge-layout detection. int64 words: [a_lo,a_hi,b_lo,b_hi,...], hi==0 always.
// int32 words: odd words random in [0,V). 64 zero odd words => int64.
// ---------------------------------------------------------------------------
__global__ void detect_kernel(const int* __restrict__ edges, int* __restrict__ flag) {
    int v = edges[2 * threadIdx.x + 1];
    unsigned long long any = __ballot(v != 0);
    if (threadIdx.x == 0) *flag = (any == 0ull) ? 1 : 0;  // 1 = int64 layout
}

__device__ __forceinline__ unsigned f2bf1(float f) {  // RNE fp32 -> bf16 bits
    unsigned u = __float_as_uint(f);
    return (u + 0x7fffu + ((u >> 16) & 1u)) >> 16;
}

__device__ __forceinline__ short8 pack_bf8(float4 a, float4 b) {
    short8 r;
    r[0] = (short)f2bf1(a.x); r[1] = (short)f2bf1(a.y);
    r[2] = (short)f2bf1(a.z); r[3] = (short)f2bf1(a.w);
    r[4] = (short)f2bf1(b.x); r[5] = (short)f2bf1(b.y);
    r[6] = (short)f2bf1(b.z); r[7] = (short)f2bf1(b.w);
    return r;
}

// verts (fp32) -> vbf (bf16-packed rows, 2 features per uint, 128 B/row)
__global__ void prep_kernel(const float* __restrict__ verts, uint2* __restrict__ vbf) {
    long i = (long)blockIdx.x * blockDim.x + threadIdx.x;
    if (i < (long)NV * (DIM / 4)) {
        float4 v = ((const float4*)verts)[i];
        uint2 w;
        w.x = f2bf1(v.x) | (f2bf1(v.y) << 16);
        w.y = f2bf1(v.z) | (f2bf1(v.w) << 16);
        vbf[i] = w;
    }
}

// ---------------------------------------------------------------------------
// Phase A (R11, verified): bin directed endpoints by target partition.
// Entry = (t_local<<17)|n. LDS-aggregated counts -> 1 global atomic per
// (block,bucket) -> sequential packed writes.
// ---------------------------------------------------------------------------
__global__ __launch_bounds__(256)
void bin_kernel(const int* __restrict__ edges, unsigned* __restrict__ bins,
                int* __restrict__ bcur, const int* __restrict__ flag) {
    __shared__ int lcnt[NXCD], lbase[NXCD];
    const bool is64 = (*flag != 0);
    const int tid = threadIdx.x;
    const long lo = (long)blockIdx.x * CHUNK;
    const long hi = (lo + CHUNK < NE) ? lo + CHUNK : NE;

    if (tid < NXCD) lcnt[tid] = 0;
    __syncthreads();

    for (long e = lo + tid; e < hi; e += 256) {
        int a, b;
        if (is64) { int4 q = ((const int4*)edges)[e]; a = q.x; b = q.z; }
        else      { int2 q = ((const int2*)edges)[e]; a = q.x; b = q.y; }
        atomicAdd(&lcnt[a / VPERX], 1);
        atomicAdd(&lcnt[b / VPERX], 1);
    }
    __syncthreads();
    if (tid < NXCD) lbase[tid] = atomicAdd(&bcur[tid], lcnt[tid]);
    __syncthreads();
    if (tid < NXCD) lcnt[tid] = 0;      // reuse as local cursor
    __syncthreads();

    for (long e = lo + tid; e < hi; e += 256) {
        int a, b;
        if (is64) { int4 q = ((const int4*)edges)[e]; a = q.x; b = q.z; }
        else      { int2 q = ((const int2*)edges)[e]; a = q.x; b = q.y; }
        const int pa = a / VPERX, pb = b / VPERX;
        int ia = lbase[pa] + atomicAdd(&lcnt[pa], 1);
        if (ia < CAPB) bins[(long)pa * CAPB + ia] =
            ((unsigned)(a - pa * VPERX) << 17) | (unsigned)b;
        int ib = lbase[pb] + atomicAdd(&lcnt[pb], 1);
        if (ib < CAPB) bins[(long)pb * CAPB + ib] =
            ((unsigned)(b - pb * VPERX) << 17) | (unsigned)a;
    }
}

// ---------------------------------------------------------------------------
// Fused scatter: XCD x's sub-grid consumes bin x in 64-entry chunks.
// Per entry (wave-uniform after shfl broadcast): all 64 lanes gather the
// bf16 row vbf[n] (lane l reads word l>>1, extracts half l&1; 128B coalesced,
// nontemporal -> no L2 allocate) and atomicAdd into sums[t*64+l] (fp32,
// partition L2-resident). lane0 counts degree. Inner bound `lim` is wave-
// uniform; every __shfl runs under full exec.
// ---------------------------------------------------------------------------
__global__ __launch_bounds__(256)
void scatter_kernel(const unsigned* __restrict__ bins, const int* __restrict__ bcur,
                    const unsigned* __restrict__ vbfw,
                    float* __restrict__ sums, int* __restrict__ cnt) {
    const int xcd = blockIdx.x & (NXCD - 1);
    const int lane = threadIdx.x & 63;
    const int wavein = (blockIdx.x >> 3) * (blockDim.x >> 6) + (threadIdx.x >> 6);
    const int nwav = (gridDim.x >> 3) * (blockDim.x >> 6);
    const int vlo = xcd * VPERX;
    int nent = bcur[xcd]; if (nent > CAPB) nent = CAPB;
    const unsigned* mybin = bins + (long)xcd * CAPB;

    const int nchunk = (nent + 63) >> 6;
    for (int ch = wavein; ch < nchunk; ch += nwav) {
        const int base = ch << 6;
        const int lim = min(64, nent - base);            // wave-uniform
        const int myidx = base + (lane < lim ? lane : 0);
        const unsigned myent = mybin[myidx];             // full-exec load

        for (int i = 0; i < lim; ++i) {                  // wave-uniform bound
            const unsigned e = __shfl(myent, i, 64);     // full exec
            const int t = vlo + (int)(e >> 17);
            const int n = (int)(e & 0x1FFFFu);
            const unsigned w =
                __builtin_nontemporal_load(&vbfw[(long)n * 32 + (lane >> 1)]);
            const float val =
                __uint_as_float((lane & 1) ? (w & 0xffff0000u) : (w << 16));
            atomicAdd(&sums[(long)t * DIM + lane], val);
            if (lane == 0) atomicAdd(&cnt[t], 1);
        }
    }
}

// ---------------------------------------------------------------------------
// MFMA matvec (R10, verified): out = [X|S]@[W0;W1]^T + b0 + deg*b1 via
// mfma_f32_16x16x32_bf16, one wave per 16-vertex tile, B-frags hoisted.
// ---------------------------------------------------------------------------
__global__ __launch_bounds__(256)
void matvec_mfma_kernel(const uint2* __restrict__ vbf,
                        const float* __restrict__ sums,
                        const float* __restrict__ w0,
                        const float* __restrict__ b0,
                        const float* __restrict__ w1,
                        const float* __restrict__ b1,
                        const int* __restrict__ cnt,
                        float* __restrict__ out) {
    const int lane = threadIdx.x & 63;
    const int quad = lane >> 4;
    const int n = lane & 15;
    const int wave = (int)((blockIdx.x * blockDim.x + threadIdx.x) >> 6);
    const int nwaves = (int)((gridDim.x * blockDim.x) >> 6);

    short8 B[4][4];
#pragma unroll
    for (int c = 0; c < 4; ++c) {
        const float* wsrc = (c < 2) ? w0 : w1;
        const int kb = (c & 1) * 32 + quad * 8;
#pragma unroll
        for (int t = 0; t < 4; ++t) {
            const int d = t * 16 + n;
            const float4 p = *(const float4*)(wsrc + d * DIM + kb);
            const float4 q = *(const float4*)(wsrc + d * DIM + kb + 4);
            B[c][t] = pack_bf8(p, q);
        }
    }
    float bias0[4], bias1[4];
#pragma unroll
    for (int t = 0; t < 4; ++t) { bias0[t] = b0[t * 16 + n]; bias1[t] = b1[t * 16 + n]; }

    const short8* vb8 = (const short8*)vbf;

    for (int tile = wave; tile < NTILE; tile += nwaves) {
        const int base = tile * 16;
        const long v = base + n;
        f32x4 acc[4] = {{0.f,0.f,0.f,0.f},{0.f,0.f,0.f,0.f},
                        {0.f,0.f,0.f,0.f},{0.f,0.f,0.f,0.f}};

#pragma unroll
        for (int c = 0; c < 2; ++c) {
            const short8 A = vb8[v * 8 + c * 4 + quad];
#pragma unroll
            for (int t = 0; t < 4; ++t)
                acc[t] = __builtin_amdgcn_mfma_f32_16x16x32_bf16(A, B[c][t], acc[t], 0, 0, 0);
        }
#pragma unroll
        for (int c = 2; c < 4; ++c) {
            const int kb = (c - 2) * 32 + quad * 8;
            const float4 p = *(const float4*)(sums + v * DIM + kb);
            const float4 q = *(const float4*)(sums + v * DIM + kb + 4);
            const short8 A = pack_bf8(p, q);
#pragma unroll
            for (int t = 0; t < 4; ++t)
                acc[t] = __builtin_amdgcn_mfma_f32_16x16x32_bf16(A, B[c][t], acc[t], 0, 0, 0);
        }
#pragma unroll
        for (int r = 0; r < 4; ++r) {
            const int row = base + quad * 4 + r;
            const float dg = (float)cnt[row];
#pragma unroll
            for (int t = 0; t < 4; ++t)
                out[(long)row * DIM + t * 16 + n] = acc[t][r] + fmaf(dg, bias1[t], bias0[t]);
        }
    }
}

// ==========================================================================

extern "C" void kernel_launch(void* const* d_in, const int* in_sizes, int n_in,
                              void* d_out, int out_size, void* d_ws, size_t ws_size,
                              hipStream_t stream) {
    const float* verts = (const float*)d_in[0];
    const int*   edges = (const int*)d_in[1];
    const float* w0_w  = (const float*)d_in[2];
    const float* w0_b  = (const float*)d_in[3];
    const float* w1_w  = (const float*)d_in[4];
    const float* w1_b  = (const float*)d_in[5];
    float* out = (float*)d_out;

    // Workspace: [sums 25.6MB][cnt 0.4MB][bcur][flag][vbf 12.8MB][bins 16.8MB]
    // = ~55.7MB (no aliasing: bins live while sums is written).
    char* p = (char*)d_ws;
    float* sums  = (float*)p;  p += (size_t)NV * DIM * 4;
    int* cnt     = (int*)p;    p += (size_t)NV * 4;
    int* bcur    = (int*)p;    p += NXCD * 4;
    int* flag    = (int*)p;    p += 16;
    uint2* vbf   = (uint2*)p;  p += (size_t)NV * DIM * 2;
    unsigned* bins = (unsigned*)p;

    // One memset covers sums + cnt + bcur (contiguous).
    hipMemsetAsync(sums, 0, (size_t)NV * DIM * 4 + (size_t)NV * 4 + NXCD * 4, stream);
    detect_kernel<<<1, 64, 0, stream>>>(edges, flag);
    prep_kernel<<<(NV * (DIM / 4) + 255) / 256, 256, 0, stream>>>(verts, vbf);
    bin_kernel<<<ABLK, 256, 0, stream>>>(edges, bins, bcur, flag);
    // 2048 blocks = 8 XCD sub-grids x 256 blocks; 1024 waves per XCD
    scatter_kernel<<<2048, 256, 0, stream>>>(bins, bcur, (const unsigned*)vbf,
                                             sums, cnt);
    matvec_mfma_kernel<<<1563, 256, 0, stream>>>(vbf, sums, w0_w, w0_b,
                                                 w1_w, w1_b, cnt, out);
}